// Round 1
// baseline (334.256 us; speedup 1.0000x reference)
//
#include <hip/hip_runtime.h>
#include <stdint.h>

// Gator: logic-gate network forward, bit-packed over batch.
//
// R5: producer/consumer split. The fused kernel's write phase ran at only
// ~2.4 TB/s effective because it was locked to 1 block/CU (grid=256 is forced
// by the 36KB LDS pack tile) and serialized behind the latency-bound pack +
// barrier-bound gate phases. Split:
//   K1 gator_pack  : phases A+B (unchanged, verified) -> 9.4 MB bit matrix in ws
//   K2 gator_unpack: fill-shaped streamer, 2304 blocks x 256 thr (9 blocks/CU),
//                    1KB/wave coalesced NT float4 stores of the 302 MB output.
// Extra HBM traffic from the ws round-trip: +18.9 MB (~3 us) -- the packed
// matrix is L2/L3 resident anyway.
// Floor: 302MB write + 33.5MB read + 18.9MB ws ~= 57 us @ 6.3 TB/s.
// Fallback to the R3 fused kernel if ws is too small.

constexpr int B    = 8192;
constexpr int W0   = 1024;
constexpr int R    = 8;
constexpr int G    = 1024;
constexpr int WTOT = W0 + R * G;   // 9216
constexpr int BPB  = 32;           // batch bits per pack group
constexpr int NBG  = B / BPB;      // 256 pack groups

typedef float vfloat4 __attribute__((ext_vector_type(4)));

// ---------------- K1: pack x into bit columns, run 8 gate rows --------------
__launch_bounds__(1024, 1)
__global__ void gator_pack(const float* __restrict__ x,
                           const float* __restrict__ gates,
                           const int*   __restrict__ choices,
                           uint32_t*    __restrict__ packed) {
    __shared__ uint32_t cols[WTOT];      // bit b of cols[w] = (batch b0+b, col w)

    const int tid  = threadIdx.x;
    const int lane = tid & 63;
    const int wv   = tid >> 6;           // wave id 0..15
    const int bg   = blockIdx.x;
    const int half = lane >> 5;          // 0: lanes 0-31, 1: lanes 32-63
    const int row  = bg * BPB + (lane & 31);

    // Prefetch gate metadata for all 8 rows into registers (overlaps phase A,
    // keeps the 8x L2-latency loads off the barrier-serial chain).
    const int2*   ch2 = (const int2*)choices;    // [R*G] index pairs
    const float4* g4  = (const float4*)gates;    // [R*G] truth tables
    int2     ch[R];
    uint32_t tt[R];                              // 4-bit truth table mask
    #pragma unroll
    for (int r = 0; r < R; ++r) {
        ch[r] = ch2[r * G + tid];
        float4 lt = g4[r * G + tid];
        tt[r] = (lt.x != 0.0f ? 1u : 0u) | (lt.y != 0.0f ? 2u : 0u) |
                (lt.z != 0.0f ? 4u : 0u) | (lt.w != 0.0f ? 8u : 0u);
    }

    // ---- Phase A: pack x[32 rows][1024 cols] into bit columns ----
    {
        const float4* xrow = (const float4*)(x + (size_t)row * W0);
        #pragma unroll
        for (int it = 0; it < 8; ++it) {
            int c = wv * 64 + it * 8 + half * 4;
            float4 v = xrow[c >> 2];
            unsigned long long m0 = __ballot(v.x != 0.0f);
            unsigned long long m1 = __ballot(v.y != 0.0f);
            unsigned long long m2 = __ballot(v.z != 0.0f);
            unsigned long long m3 = __ballot(v.w != 0.0f);
            if ((lane & 31) == 0) {      // lane 0 -> cols c..c+3, lane 32 -> c+4..c+7
                int s = half * 32;
                cols[c + 0] = (uint32_t)(m0 >> s);
                cols[c + 1] = (uint32_t)(m1 >> s);
                cols[c + 2] = (uint32_t)(m2 >> s);
                cols[c + 3] = (uint32_t)(m3 >> s);
            }
        }
    }
    __syncthreads();

    // ---- Phase B: 8 gate rows, one gate per thread per row ----
    #pragma unroll
    for (int r = 0; r < R; ++r) {
        uint32_t a = cols[ch[r].x];
        uint32_t b = cols[ch[r].y];
        uint32_t m0 = 0u - (tt[r] & 1u);
        uint32_t m1 = 0u - ((tt[r] >> 1) & 1u);
        uint32_t m2 = 0u - ((tt[r] >> 2) & 1u);
        uint32_t m3 = 0u - ((tt[r] >> 3) & 1u);
        uint32_t o = (m0 & ~a & ~b) | (m1 & ~a & b) | (m2 & a & ~b) | (m3 & a & b);
        cols[W0 + r * G + tid] = o;
        __syncthreads();
    }

    // ---- Dump packed columns (9216 words = 36 KB/block, coalesced 16B) ----
    // Regular (cached) stores: K2 re-reads this through L2/L3 immediately.
    uint32_t* prow = packed + (size_t)bg * WTOT;
    for (int w = tid * 4; w < WTOT; w += 4096) {
        *(uint4*)&prow[w] = *(const uint4*)&cols[w];
    }
}

// ---------------- K2: streaming unpack (fill-shaped) ------------------------
// Grid (9, 256): block (chunk, bg) expands packed[bg][chunk*1024 .. +1024)
// into 32 batch rows of float output. Per thread: one 16B packed read,
// 32 coalesced 1KB/wave NT float4 stores. 9 blocks/CU -> store stream always
// saturated, no pack/gate serialization in front of it.
__launch_bounds__(256, 8)
__global__ void gator_unpack(const uint32_t* __restrict__ packed,
                             float*          __restrict__ out) {
    const int w  = blockIdx.x * 1024 + threadIdx.x * 4;   // column
    const int bg = blockIdx.y;                            // pack group

    uint4 c = *(const uint4*)&packed[(size_t)bg * WTOT + w];
    float* orow = out + (size_t)bg * BPB * WTOT + w;
    #pragma unroll
    for (int b = 0; b < BPB; ++b) {
        vfloat4 v;
        v.x = (float)((c.x >> b) & 1u);
        v.y = (float)((c.y >> b) & 1u);
        v.z = (float)((c.z >> b) & 1u);
        v.w = (float)((c.w >> b) & 1u);
        __builtin_nontemporal_store(v, (vfloat4*)(orow + (size_t)b * WTOT));
    }
}

// ---------------- Fallback: R3 fused kernel (verified winner) ---------------
__launch_bounds__(1024, 1)
__global__ void gator_fused(const float* __restrict__ x,
                            const float* __restrict__ gates,
                            const int*   __restrict__ choices,
                            float*       __restrict__ out) {
    __shared__ uint32_t cols[WTOT];

    const int tid  = threadIdx.x;
    const int lane = tid & 63;
    const int wv   = tid >> 6;
    const int bg   = blockIdx.x;
    const int half = lane >> 5;
    const int row  = bg * BPB + (lane & 31);

    const int2*   ch2 = (const int2*)choices;
    const float4* g4  = (const float4*)gates;
    int2     ch[R];
    uint32_t tt[R];
    #pragma unroll
    for (int r = 0; r < R; ++r) {
        ch[r] = ch2[r * G + tid];
        float4 lt = g4[r * G + tid];
        tt[r] = (lt.x != 0.0f ? 1u : 0u) | (lt.y != 0.0f ? 2u : 0u) |
                (lt.z != 0.0f ? 4u : 0u) | (lt.w != 0.0f ? 8u : 0u);
    }

    {
        const float4* xrow = (const float4*)(x + (size_t)row * W0);
        #pragma unroll
        for (int it = 0; it < 8; ++it) {
            int c = wv * 64 + it * 8 + half * 4;
            float4 v = xrow[c >> 2];
            unsigned long long m0 = __ballot(v.x != 0.0f);
            unsigned long long m1 = __ballot(v.y != 0.0f);
            unsigned long long m2 = __ballot(v.z != 0.0f);
            unsigned long long m3 = __ballot(v.w != 0.0f);
            if ((lane & 31) == 0) {
                int s = half * 32;
                cols[c + 0] = (uint32_t)(m0 >> s);
                cols[c + 1] = (uint32_t)(m1 >> s);
                cols[c + 2] = (uint32_t)(m2 >> s);
                cols[c + 3] = (uint32_t)(m3 >> s);
            }
        }
    }
    __syncthreads();

    #pragma unroll
    for (int r = 0; r < R; ++r) {
        uint32_t a = cols[ch[r].x];
        uint32_t b = cols[ch[r].y];
        uint32_t m0 = 0u - (tt[r] & 1u);
        uint32_t m1 = 0u - ((tt[r] >> 1) & 1u);
        uint32_t m2 = 0u - ((tt[r] >> 2) & 1u);
        uint32_t m3 = 0u - ((tt[r] >> 3) & 1u);
        uint32_t o = (m0 & ~a & ~b) | (m1 & ~a & b) | (m2 & a & ~b) | (m3 & a & b);
        cols[W0 + r * G + tid] = o;
        __syncthreads();
    }

    for (int w = tid * 4; w < WTOT; w += 4096) {
        uint4 c = *(const uint4*)&cols[w];
        float* orow = out + (size_t)bg * BPB * WTOT + w;
        #pragma unroll
        for (int b = 0; b < BPB; ++b) {
            vfloat4 v;
            v.x = (float)((c.x >> b) & 1u);
            v.y = (float)((c.y >> b) & 1u);
            v.z = (float)((c.z >> b) & 1u);
            v.w = (float)((c.w >> b) & 1u);
            __builtin_nontemporal_store(v, (vfloat4*)(orow + (size_t)b * WTOT));
        }
    }
}

extern "C" void kernel_launch(void* const* d_in, const int* in_sizes, int n_in,
                              void* d_out, int out_size, void* d_ws, size_t ws_size,
                              hipStream_t stream) {
    const float* x       = (const float*)d_in[0];
    const float* gates   = (const float*)d_in[1];
    const int*   choices = (const int*)d_in[2];
    float*       out     = (float*)d_out;

    const size_t packed_bytes = (size_t)NBG * WTOT * sizeof(uint32_t); // 9.44 MB
    if (d_ws != nullptr && ws_size >= packed_bytes) {
        uint32_t* packed = (uint32_t*)d_ws;
        gator_pack<<<dim3(NBG), dim3(1024), 0, stream>>>(x, gates, choices, packed);
        gator_unpack<<<dim3(WTOT / 1024, NBG), dim3(256), 0, stream>>>(packed, out);
    } else {
        gator_fused<<<dim3(B / BPB), dim3(1024), 0, stream>>>(x, gates, choices, out);
    }
}